// Round 3
// baseline (232.193 us; speedup 1.0000x reference)
//
#include <hip/hip_runtime.h>

#define NB 8
#define NC 2048
#define KIN 128
#define NF 64

#define WTSTRIDE 136          // k1 LDS W^T row stride (ushorts)
#define RSTRIDE 68            // k2 reduce row stride (floats)
#define MOFF 60.0f            // softmax shift slack: p <= e^60
#define LOG2E 1.44269504088896340736f

typedef float floatx4_t __attribute__((ext_vector_type(4)));
typedef __bf16 bf16x8_t __attribute__((ext_vector_type(8)));
typedef unsigned short ushort8_t __attribute__((ext_vector_type(8)));

static __device__ __forceinline__ unsigned short f2bf(float f) {
  union { float f; unsigned int u; } v; v.f = f;
  unsigned int u = v.u;
  u += 0x7FFFu + ((u >> 16) & 1u);   // RNE; inputs never NaN
  return (unsigned short)(u >> 16);
}

static __device__ __forceinline__ float lrelu(float x) {
  return fmaxf(x, 0.2f * x);
}

// ---------------------------------------------------------------------------
// Kernel 1: per block = 16 rows of one batch (1024 blocks -> 4 blocks/CU).
//   - w1 = W@a1, w2 = W@a2; s1/s2 fp32-exact (16 threads per row)
//   - WhT[b,f,c] = bf16((H@W)^T) via MFMA: D = W^T (f x k) · H^T (k x c);
//     waves split the f dimension (wave w owns f rows w*16..w*16+15).
// ---------------------------------------------------------------------------
__global__ __launch_bounds__(256, 4) void k1_prep(
    const float* __restrict__ H, const float* __restrict__ W,
    const float* __restrict__ avec,
    float* __restrict__ s1g, float* __restrict__ s2g,
    unsigned short* __restrict__ WhT)
{
  __shared__ unsigned short WTsh[NF * WTSTRIDE];   // 17.4 KB
  __shared__ float w1sh[KIN];
  __shared__ float w2sh[KIN];

  const int t = threadIdx.x;
  const int b = blockIdx.x >> 7;
  const int c0 = (blockIdx.x & 127) * 16;

  // build bf16 W^T in LDS (coalesced global read)
  for (int i = t; i < KIN * NF; i += 256) {
    int k = i >> 6, f = i & 63;
    WTsh[f * WTSTRIDE + k] = f2bf(W[i]);
  }
  // w1/w2 (fp32 exact)
  if (t < KIN) {
    float acc1 = 0.f, acc2 = 0.f;
    const float* wr = W + t * NF;
#pragma unroll
    for (int f = 0; f < NF; ++f) {
      float wv = wr[f];
      acc1 += wv * avec[f];
      acc2 += wv * avec[NF + f];
    }
    w1sh[t] = acc1;
    w2sh[t] = acc2;
  }
  __syncthreads();

  // ---- phase 1: s1/s2, 16 threads per row, 8 cols each ----
  {
    const int r = t >> 4;          // 0..15
    const int x = t & 15;
    const float* hp = H + (size_t)(b * NC + c0 + r) * KIN + x * 8;
    float4 h0 = *(const float4*)(hp);
    float4 h1 = *(const float4*)(hp + 4);
    float4 u10 = *(const float4*)(w1sh + x * 8);
    float4 u11 = *(const float4*)(w1sh + x * 8 + 4);
    float4 u20 = *(const float4*)(w2sh + x * 8);
    float4 u21 = *(const float4*)(w2sh + x * 8 + 4);
    float p1 = h0.x * u10.x + h0.y * u10.y + h0.z * u10.z + h0.w * u10.w
             + h1.x * u11.x + h1.y * u11.y + h1.z * u11.z + h1.w * u11.w;
    float p2 = h0.x * u20.x + h0.y * u20.y + h0.z * u20.z + h0.w * u20.w
             + h1.x * u21.x + h1.y * u21.y + h1.z * u21.z + h1.w * u21.w;
#pragma unroll
    for (int off = 1; off < 16; off <<= 1) {
      p1 += __shfl_xor(p1, off);
      p2 += __shfl_xor(p2, off);
    }
    if (x == 0) {
      s1g[b * NC + c0 + r] = p1;
      s2g[b * NC + c0 + r] = p2;
    }
  }

  // ---- phase 2: MFMA, D = W^T · H^T; wave w owns f rows w*16..w*16+15 ----
  const int wave = t >> 6;
  const int lane = t & 63;
  const int m = lane & 15;   // A-row (f sub) and B-col (c sub)
  const int q = lane >> 4;
  floatx4_t acc = (floatx4_t){0.f, 0.f, 0.f, 0.f};

  const float* hb = H + (size_t)(b * NC + c0 + m) * KIN;
#pragma unroll
  for (int kt = 0; kt < 4; ++kt) {
    const int kbase = kt * 32 + q * 8;
    float4 h0 = *(const float4*)(hb + kbase);
    float4 h1 = *(const float4*)(hb + kbase + 4);
    ushort8_t bu;
    bu[0] = f2bf(h0.x); bu[1] = f2bf(h0.y); bu[2] = f2bf(h0.z); bu[3] = f2bf(h0.w);
    bu[4] = f2bf(h1.x); bu[5] = f2bf(h1.y); bu[6] = f2bf(h1.z); bu[7] = f2bf(h1.w);
    bf16x8_t bf = __builtin_bit_cast(bf16x8_t, bu);
    ushort8_t au = *(const ushort8_t*)(WTsh + (wave * 16 + m) * WTSTRIDE + kbase);
    bf16x8_t af = __builtin_bit_cast(bf16x8_t, au);
    acc = __builtin_amdgcn_mfma_f32_16x16x32_bf16(af, bf, acc, 0, 0, 0);
  }
  // D[row = q*4+i2 -> f sub][col = m -> c]
#pragma unroll
  for (int i2 = 0; i2 < 4; ++i2) {
    const int f = wave * 16 + q * 4 + i2;
    WhT[(size_t)(b * NF + f) * NC + c0 + m] = f2bf(acc[i2]);
  }
}

// ---------------------------------------------------------------------------
// Kernel 2: per block = 16 query rows of one batch. Single pass over A:
// mask -> exp2 -> bf16(trunc) -> MFMA (4 Wh tiles + ones-tile for row sums).
// ---------------------------------------------------------------------------
__global__ __launch_bounds__(256, 4) void k2_attn(
    const int* __restrict__ A, const float* __restrict__ s1g,
    const float* __restrict__ s2g, const unsigned short* __restrict__ WhT,
    float* __restrict__ out)
{
  __shared__ float s2_sh[NC];                   // 8 KB
  __shared__ float s1_sh[16];
  __shared__ float wmax_sh[4];
  __shared__ float red_sh[4 * 16 * RSTRIDE];    // 17.4 KB
  __shared__ float lsum_sh[4 * 16];

  const int t = threadIdx.x;
  const int b = blockIdx.x >> 7;
  const int i0 = (blockIdx.x & 127) * 16;
  const int wave = t >> 6;
  const int lane = t & 63;

  // stage s2 (two coalesced float4 sweeps) + batch-max of s2
  float lmax;
  {
    const float* sp = s2g + b * NC;
    float4 v0 = *(const float4*)(sp + t * 4);
    float4 v1 = *(const float4*)(sp + 1024 + t * 4);
    *(float4*)(s2_sh + t * 4) = v0;
    *(float4*)(s2_sh + 1024 + t * 4) = v1;
    lmax = fmaxf(fmaxf(fmaxf(v0.x, v0.y), fmaxf(v0.z, v0.w)),
                 fmaxf(fmaxf(v1.x, v1.y), fmaxf(v1.z, v1.w)));
#pragma unroll
    for (int off = 1; off < 64; off <<= 1)
      lmax = fmaxf(lmax, __shfl_xor(lmax, off));
    if (lane == 0) wmax_sh[wave] = lmax;
  }
  if (t < 16) s1_sh[t] = s1g[b * NC + i0 + t];
  __syncthreads();

  const float s2max =
      fmaxf(fmaxf(wmax_sh[0], wmax_sh[1]), fmaxf(wmax_sh[2], wmax_sh[3]));

  const int m = lane & 15;   // A-frag row (query sub) and B-frag col (f sub)
  const int q = lane >> 4;
  const int gi = i0 + m;
  const float s1m = s1_sh[m];
  // exp(l - mm) == exp2(l*log2e - mmL), mm = upper bound minus slack
  const float mmL = (lrelu(s1m + s2max) - MOFF) * LOG2E;
  const int* Ap = A + ((size_t)b * NC + gi) * NC;
  const unsigned short* whb = WhT + (size_t)b * NF * NC;

  // ones B-fragment: column 0 of tile = 1.0 -> accl col0 = row sums of P
  ushort8_t ou;
  {
    const unsigned short ov = (m == 0) ? (unsigned short)0x3F80 : (unsigned short)0;
#pragma unroll
    for (int idx = 0; idx < 8; ++idx) ou[idx] = ov;
  }
  const bf16x8_t onesf = __builtin_bit_cast(bf16x8_t, ou);

  floatx4_t acc[4], accl;
#pragma unroll
  for (int nt = 0; nt < 4; ++nt) acc[nt] = (floatx4_t){0.f, 0.f, 0.f, 0.f};
  accl = (floatx4_t){0.f, 0.f, 0.f, 0.f};

  const int ktBeg = wave * 16;
  // A prefetch, depth 2 (64 B/lane in flight)
  int4 abuf[2][2];
  {
    const int* ap0 = Ap + ktBeg * 32 + q * 8;
    abuf[0][0] = *(const int4*)ap0;
    abuf[0][1] = *(const int4*)(ap0 + 4);
    const int* ap1 = ap0 + 32;
    abuf[1][0] = *(const int4*)ap1;
    abuf[1][1] = *(const int4*)(ap1 + 4);
  }

#pragma unroll 2
  for (int kk = 0; kk < 16; ++kk) {
    const int kt = ktBeg + kk;
    const int jq = kt * 32 + q * 8;
    const int cur = kk & 1;
    const int4 a0 = abuf[cur][0];
    const int4 a1 = abuf[cur][1];
    if (kk + 2 < 16) {
      const int* ap = Ap + (kt + 2) * 32 + q * 8;
      abuf[cur][0] = *(const int4*)ap;
      abuf[cur][1] = *(const int4*)(ap + 4);
    }
    // WhT fragments: issue before the VALU block so L2 latency is covered
    ushort8_t whc[4];
#pragma unroll
    for (int nt = 0; nt < 4; ++nt)
      whc[nt] = *(const ushort8_t*)(whb + (size_t)(nt * 16 + m) * NC + jq);

    float4 s0 = *(const float4*)(s2_sh + jq);
    float4 s1v = *(const float4*)(s2_sh + jq + 4);
    const float sv[8] = {s0.x, s0.y, s0.z, s0.w, s1v.x, s1v.y, s1v.z, s1v.w};
    const int av[8] = {a0.x, a0.y, a0.z, a0.w, a1.x, a1.y, a1.z, a1.w};
    const int d = gi - jq;   // diagonal hits when d == idx (0..7)
    unsigned int pu[8];
#pragma unroll
    for (int idx = 0; idx < 8; ++idx) {
      float x = s1m + sv[idx];
      float p = __builtin_amdgcn_exp2f(fmaf(lrelu(x), LOG2E, -mmL));
      bool keep = (av[idx] > 0) || (d == idx);
      p = keep ? p : 0.0f;
      pu[idx] = __builtin_bit_cast(unsigned int, p);
    }
    // truncating bf16 pack (bias cancels in alpha: same p feeds ones-MFMA)
    uint4 pk;
    pk.x = __builtin_amdgcn_perm(pu[1], pu[0], 0x07060302u);
    pk.y = __builtin_amdgcn_perm(pu[3], pu[2], 0x07060302u);
    pk.z = __builtin_amdgcn_perm(pu[5], pu[4], 0x07060302u);
    pk.w = __builtin_amdgcn_perm(pu[7], pu[6], 0x07060302u);
    const bf16x8_t af = __builtin_bit_cast(bf16x8_t, pk);
#pragma unroll
    for (int nt = 0; nt < 4; ++nt) {
      bf16x8_t bf = __builtin_bit_cast(bf16x8_t, whc[nt]);
      acc[nt] = __builtin_amdgcn_mfma_f32_16x16x32_bf16(af, bf, acc[nt], 0, 0, 0);
    }
    accl = __builtin_amdgcn_mfma_f32_16x16x32_bf16(af, onesf, accl, 0, 0, 0);
  }

  // cross-wave reduce: acc D[row=q*4+i2][col=m(+nt*16)], lsum from accl col 0
#pragma unroll
  for (int nt = 0; nt < 4; ++nt) {
#pragma unroll
    for (int i2 = 0; i2 < 4; ++i2) {
      red_sh[wave * (16 * RSTRIDE) + (q * 4 + i2) * RSTRIDE + nt * 16 + m] =
          acc[nt][i2];
    }
  }
  if (m == 0) {
#pragma unroll
    for (int i2 = 0; i2 < 4; ++i2)
      lsum_sh[wave * 16 + q * 4 + i2] = accl[i2];
  }
  __syncthreads();

  {
    const int row = t >> 4;
    const int f0 = (t & 15) * 4;
    float4 v = {0.f, 0.f, 0.f, 0.f};
    float ls = 0.f;
#pragma unroll
    for (int w = 0; w < 4; ++w) {
      const float* rp = red_sh + w * (16 * RSTRIDE) + row * RSTRIDE + f0;
      float4 vv = *(const float4*)rp;
      v.x += vv.x; v.y += vv.y; v.z += vv.z; v.w += vv.w;
      ls += lsum_sh[w * 16 + row];
    }
    const float inv = 1.0f / ls;
    float4 o;
    o.x = fmaxf(v.x * inv, 0.f);
    o.y = fmaxf(v.y * inv, 0.f);
    o.z = fmaxf(v.z * inv, 0.f);
    o.w = fmaxf(v.w * inv, 0.f);
    *(float4*)(out + (size_t)(b * NC + i0 + row) * NF + f0) = o;
  }
}

extern "C" void kernel_launch(void* const* d_in, const int* in_sizes, int n_in,
                              void* d_out, int out_size, void* d_ws, size_t ws_size,
                              hipStream_t stream) {
  const float* H = (const float*)d_in[0];
  const int* A = (const int*)d_in[1];
  const float* W = (const float*)d_in[2];
  const float* avec = (const float*)d_in[3];
  float* out = (float*)d_out;

  char* ws = (char*)d_ws;
  unsigned short* WhT = (unsigned short*)ws;                    // 2 MB
  float* s1 = (float*)(ws + (size_t)NB * NF * NC * 2);          // 64 KB
  float* s2 = s1 + NB * NC;                                     // 64 KB

  k1_prep<<<dim3(NB * (NC / 16)), dim3(256), 0, stream>>>(H, W, avec, s1, s2, WhT);
  k2_attn<<<dim3(NB * (NC / 16)), dim3(256), 0, stream>>>(A, s1, s2, WhT, out);
}